// Round 1
// baseline (182.146 us; speedup 1.0000x reference)
//
#include <hip/hip_runtime.h>
#include <math.h>

#define ALPHA_F 0.02f

constexpr int Bn  = 32;
constexpr int Cn  = 512;
constexpr int CRn = 32;    // C / 16
constexpr int HWn = 4096;  // 64*64
constexpr int NCG = 8;     // channel groups of 64 channels
constexpr int NPG = 4;     // pixel groups of 1024 pixels

__device__ __forceinline__ float sigmoidf_(float v) {
    return 1.0f / (1.0f + expf(-v));
}

// ---------------------------------------------------------------------------
// K1: one pass over x. Computes
//   cps/cpm: channel partial sum/max  [NPG][B][C]   (partial over 1024 pixels)
//   sps/spm: spatial partial sum/max  [NCG][B][HW]  (partial over 64 channels)
// Block = (b, cg, pg): 64 channels x 1024 pixels. 4 waves; wave owns 16 chans.
// ---------------------------------------------------------------------------
__global__ __launch_bounds__(256) void k1_reduce(
    const float* __restrict__ x,
    float* __restrict__ cps, float* __restrict__ cpm,
    float* __restrict__ sps, float* __restrict__ spm)
{
    const int bid = blockIdx.x;
    const int pg  = bid & 3;
    const int cg  = (bid >> 2) & 7;
    const int b   = bid >> 5;
    const int t    = threadIdx.x;
    const int wv   = t >> 6;
    const int lane = t & 63;

    __shared__ float ls[4][1024];
    __shared__ float lm[4][1024];

    const float* xb = x + ((size_t)b * Cn + (size_t)cg * 64) * HWn + pg * 1024;

    // per-pixel accumulators: pixel_local = 256*q + 4*lane + i
    float4 psum[4], pmax[4];
#pragma unroll
    for (int q = 0; q < 4; ++q) {
        psum[q] = make_float4(0.f, 0.f, 0.f, 0.f);
        pmax[q] = make_float4(-INFINITY, -INFINITY, -INFINITY, -INFINITY);
    }

#pragma unroll 4
    for (int cl = 0; cl < 16; ++cl) {
        const int c = wv * 16 + cl;  // channel within the 64-ch group
        const float4* row = (const float4*)(xb + (size_t)c * HWn);
        float lsum = 0.f, lmax = -INFINITY;
#pragma unroll
        for (int q = 0; q < 4; ++q) {
            const float4 v = row[q * 64 + lane];
            psum[q].x += v.x; psum[q].y += v.y; psum[q].z += v.z; psum[q].w += v.w;
            pmax[q].x = fmaxf(pmax[q].x, v.x);
            pmax[q].y = fmaxf(pmax[q].y, v.y);
            pmax[q].z = fmaxf(pmax[q].z, v.z);
            pmax[q].w = fmaxf(pmax[q].w, v.w);
            lsum += (v.x + v.y) + (v.z + v.w);
            lmax = fmaxf(lmax, fmaxf(fmaxf(v.x, v.y), fmaxf(v.z, v.w)));
        }
        // wave-level reduce over 64 lanes -> partial over 1024 pixels
#pragma unroll
        for (int m = 32; m >= 1; m >>= 1) {
            lsum += __shfl_xor(lsum, m, 64);
            lmax = fmaxf(lmax, __shfl_xor(lmax, m, 64));
        }
        if (lane == 0) {
            const int cglob = cg * 64 + c;
            cps[(pg * Bn + b) * Cn + cglob] = lsum;
            cpm[(pg * Bn + b) * Cn + cglob] = lmax;
        }
    }

    // stash per-wave pixel partials, combine across the 4 waves
    float4* lsw = (float4*)ls[wv];
    float4* lmw = (float4*)lm[wv];
#pragma unroll
    for (int q = 0; q < 4; ++q) {
        lsw[q * 64 + lane] = psum[q];
        lmw[q * 64 + lane] = pmax[q];
    }
    __syncthreads();

    float4 s  = ((const float4*)ls[0])[t];
    float4 mx = ((const float4*)lm[0])[t];
#pragma unroll
    for (int w = 1; w < 4; ++w) {
        const float4 a  = ((const float4*)ls[w])[t];
        const float4 bb = ((const float4*)lm[w])[t];
        s.x += a.x; s.y += a.y; s.z += a.z; s.w += a.w;
        mx.x = fmaxf(mx.x, bb.x); mx.y = fmaxf(mx.y, bb.y);
        mx.z = fmaxf(mx.z, bb.z); mx.w = fmaxf(mx.w, bb.w);
    }
    float4* os = (float4*)(sps + ((size_t)cg * Bn + b) * HWn + pg * 1024);
    float4* om = (float4*)(spm + ((size_t)cg * Bn + b) * HWn + pg * 1024);
    os[t] = s;
    om[t] = mx;
}

// ---------------------------------------------------------------------------
// K2a: finalize spatial stats: reduce the NCG partials -> savg, smax [B][HW]
// ---------------------------------------------------------------------------
__global__ __launch_bounds__(256) void k2_spatial_finalize(
    const float* __restrict__ sps, const float* __restrict__ spm,
    float* __restrict__ savg, float* __restrict__ smax)
{
    const int i = blockIdx.x * 256 + threadIdx.x;  // float4 index, B*HW/4 total
    const float4* ps = (const float4*)sps;
    const float4* pm = (const float4*)spm;
    float4 s = ps[i], m = pm[i];
#pragma unroll
    for (int cg = 1; cg < NCG; ++cg) {
        const float4 a  = ps[cg * (Bn * HWn / 4) + i];
        const float4 b4 = pm[cg * (Bn * HWn / 4) + i];
        s.x += a.x; s.y += a.y; s.z += a.z; s.w += a.w;
        m.x = fmaxf(m.x, b4.x); m.y = fmaxf(m.y, b4.y);
        m.z = fmaxf(m.z, b4.z); m.w = fmaxf(m.w, b4.w);
    }
    const float inv = 1.0f / (float)Cn;
    s.x *= inv; s.y *= inv; s.z *= inv; s.w *= inv;
    ((float4*)savg)[i] = s;
    ((float4*)smax)[i] = m;
}

// ---------------------------------------------------------------------------
// K2b: channel MLP. One block per batch.
// mcF[b,c] = 1-a + a*sigmoid( W2 · ( relu(W1·avg) + relu(W1·max) ) )
// ---------------------------------------------------------------------------
__global__ __launch_bounds__(256) void k2_mlp(
    const float* __restrict__ cps, const float* __restrict__ cpm,
    const float* __restrict__ w1, const float* __restrict__ w2,
    float* __restrict__ mcF)
{
    const int b = blockIdx.x;
    const int t = threadIdx.x;
    __shared__ float avg[Cn];
    __shared__ float mxv[Cn];
    __shared__ float hs[CRn];

    for (int c = t; c < Cn; c += 256) {
        float s = 0.f, m = -INFINITY;
#pragma unroll
        for (int pgi = 0; pgi < NPG; ++pgi) {
            s += cps[(pgi * Bn + b) * Cn + c];
            m = fmaxf(m, cpm[(pgi * Bn + b) * Cn + c]);
        }
        avg[c] = s * (1.0f / (float)HWn);
        mxv[c] = m;
    }
    __syncthreads();

    // hidden: 32 j's x 8 partial threads each
    const int j = t >> 3, s8 = t & 7;
    float pa = 0.f, pm = 0.f;
    const float* w1r = w1 + j * Cn + s8 * 64;
    const float* av  = avg + s8 * 64;
    const float* mv  = mxv + s8 * 64;
    for (int k = 0; k < 64; ++k) {
        pa += av[k] * w1r[k];
        pm += mv[k] * w1r[k];
    }
    pa += __shfl_xor(pa, 1, 64); pm += __shfl_xor(pm, 1, 64);
    pa += __shfl_xor(pa, 2, 64); pm += __shfl_xor(pm, 2, 64);
    pa += __shfl_xor(pa, 4, 64); pm += __shfl_xor(pm, 4, 64);
    if (s8 == 0) hs[j] = fmaxf(pa, 0.f) + fmaxf(pm, 0.f);
    __syncthreads();

    for (int c = t; c < Cn; c += 256) {
        float o = 0.f;
        const float* w2r = w2 + c * CRn;
#pragma unroll
        for (int jj = 0; jj < CRn; ++jj) o += hs[jj] * w2r[jj];
        mcF[b * Cn + c] = 1.0f - ALPHA_F + ALPHA_F * sigmoidf_(o);
    }
}

// ---------------------------------------------------------------------------
// K3: 7x7 conv on [avg;max] spatial maps -> msF[b,p] = 1-a + a*sigmoid(conv)
// One thread per output pixel; stats are L2-resident (1 MB).
// ---------------------------------------------------------------------------
__global__ __launch_bounds__(256) void k3_conv(
    const float* __restrict__ savg, const float* __restrict__ smax,
    const float* __restrict__ wconv, float* __restrict__ msF)
{
    __shared__ float wc[98];
    const int t = threadIdx.x;
    if (t < 98) wc[t] = wconv[t];
    __syncthreads();

    const int p  = blockIdx.x * 256 + t;  // 0 .. B*HW-1
    const int b  = p >> 12;
    const int pl = p & 4095;
    const int y  = pl >> 6, xc = pl & 63;
    const float* sa = savg + b * HWn;
    const float* sm = smax + b * HWn;
    float acc = 0.f;
#pragma unroll
    for (int ky = 0; ky < 7; ++ky) {
        const int yy = y + ky - 3;
        if (yy < 0 || yy >= 64) continue;
#pragma unroll
        for (int kx = 0; kx < 7; ++kx) {
            const int xx = xc + kx - 3;
            if (xx < 0 || xx >= 64) continue;
            const int off = (yy << 6) + xx;
            acc += wc[ky * 7 + kx] * sa[off] + wc[49 + ky * 7 + kx] * sm[off];
        }
    }
    msF[p] = 1.0f - ALPHA_F + ALPHA_F * sigmoidf_(acc);
}

// ---------------------------------------------------------------------------
// K4: out = x * mcF[b,c] * msF[b,p]   (float4 streaming)
// ---------------------------------------------------------------------------
__global__ __launch_bounds__(256) void k4_apply(
    const float* __restrict__ x, const float* __restrict__ mcF,
    const float* __restrict__ msF, float* __restrict__ out)
{
    const long long N4 = (long long)Bn * Cn * HWn / 4;  // 16,777,216
    const long long stride = (long long)gridDim.x * 256;
    const float4* x4  = (const float4*)x;
    const float4* ms4 = (const float4*)msF;
    float4* o4 = (float4*)out;
    for (long long v = (long long)blockIdx.x * 256 + threadIdx.x; v < N4; v += stride) {
        const int bc = (int)(v >> 10);   // b*C + c   (HW/4 = 1024 float4 per row)
        const int pq = (int)(v & 1023);  // float4 index within the row
        const int b  = bc >> 9;
        const float f = mcF[bc];
        const float4 m = ms4[b * 1024 + pq];
        float4 xv = x4[v];
        xv.x *= f * m.x; xv.y *= f * m.y; xv.z *= f * m.z; xv.w *= f * m.w;
        o4[v] = xv;
    }
}

extern "C" void kernel_launch(void* const* d_in, const int* in_sizes, int n_in,
                              void* d_out, int out_size, void* d_ws, size_t ws_size,
                              hipStream_t stream)
{
    const float* x     = (const float*)d_in[0];
    const float* w1    = (const float*)d_in[1];
    const float* w2    = (const float*)d_in[2];
    const float* wconv = (const float*)d_in[3];
    float* out = (float*)d_out;

    float* p = (float*)d_ws;
    float* cps  = p; p += NPG * Bn * Cn;   // 65536
    float* cpm  = p; p += NPG * Bn * Cn;   // 65536
    float* sps  = p; p += NCG * Bn * HWn;  // 1048576
    float* spm  = p; p += NCG * Bn * HWn;  // 1048576
    float* savg = p; p += Bn * HWn;        // 131072
    float* smax = p; p += Bn * HWn;        // 131072
    float* mcF  = p; p += Bn * Cn;         // 16384
    float* msF  = p; p += Bn * HWn;        // 131072  (total ~10.1 MB)

    hipLaunchKernelGGL(k1_reduce, dim3(Bn * NCG * NPG), dim3(256), 0, stream,
                       x, cps, cpm, sps, spm);
    hipLaunchKernelGGL(k2_spatial_finalize, dim3(Bn * HWn / 4 / 256), dim3(256), 0, stream,
                       sps, spm, savg, smax);
    hipLaunchKernelGGL(k2_mlp, dim3(Bn), dim3(256), 0, stream,
                       cps, cpm, w1, w2, mcF);
    hipLaunchKernelGGL(k3_conv, dim3(Bn * HWn / 256), dim3(256), 0, stream,
                       savg, smax, wconv, msF);
    hipLaunchKernelGGL(k4_apply, dim3(4096), dim3(256), 0, stream,
                       x, mcF, msF, out);
}